// Round 3
// baseline (1292.273 us; speedup 1.0000x reference)
//
#include <hip/hip_runtime.h>
#include <hip/hip_bf16.h>

typedef __attribute__((ext_vector_type(8))) short short8_t;
typedef __attribute__((ext_vector_type(8))) unsigned short ushort8_t;
typedef __attribute__((ext_vector_type(4))) float f32x4;

#define SCALE 0.125f   // 64^-0.5

__device__ __forceinline__ unsigned short f32_to_bf16_rne(float f) {
  unsigned int u = __float_as_uint(f);
  unsigned int r = 0x7FFFu + ((u >> 16) & 1u);
  return (unsigned short)((u + r) >> 16);
}

// ---------------- cast x (fp32 -> bf16) ----------------
__global__ __launch_bounds__(256) void cast_x_kernel(const float4* __restrict__ in,
                                                     ushort4* __restrict__ out, int n4) {
  int i = blockIdx.x * 256 + threadIdx.x;
  if (i < n4) {
    float4 v = in[i];
    ushort4 o;
    o.x = f32_to_bf16_rne(v.x); o.y = f32_to_bf16_rne(v.y);
    o.z = f32_to_bf16_rne(v.z); o.w = f32_to_bf16_rne(v.w);
    out[i] = o;
  }
}

// ---------------- transpose + cast weights: in R x C fp32 -> out C x R bf16 ----------------
__global__ __launch_bounds__(256) void transpose_cast_kernel(const float* __restrict__ in,
                                                             unsigned short* __restrict__ out,
                                                             int R, int C) {
  __shared__ float tile[32][33];
  int c0 = blockIdx.x * 32, r0 = blockIdx.y * 32;
  int tx = threadIdx.x & 31, ty = threadIdx.x >> 5;  // 32 x 8
  #pragma unroll
  for (int i = ty; i < 32; i += 8)
    tile[i][tx] = in[(long)(r0 + i) * C + c0 + tx];
  __syncthreads();
  #pragma unroll
  for (int i = ty; i < 32; i += 8)
    out[(long)(c0 + i) * R + r0 + tx] = f32_to_bf16_rne(tile[tx][i]);
}

// ---------------- transpose V out of KV buffer: Vt[b][h][d][j] = KV[b*1024+j][768+h*64+d] ----------------
__global__ __launch_bounds__(256) void transpose_v_kernel(const unsigned short* __restrict__ KV,
                                                          unsigned short* __restrict__ Vt) {
  __shared__ unsigned short tile[64][72];
  const int j0 = blockIdx.x * 64, h = blockIdx.y, b = blockIdx.z;
  const int tid = threadIdx.x;
  for (int c = tid; c < 512; c += 256) {
    int j = c >> 3, dp = (c & 7) * 8;
    *(ushort8_t*)&tile[j][dp] =
        *(const ushort8_t*)&KV[(long)(b * 1024 + j0 + j) * 1536 + 768 + h * 64 + dp];
  }
  __syncthreads();
  for (int c = tid; c < 512; c += 256) {
    int d = c >> 3, jp = (c & 7) * 8;
    ushort8_t v;
    #pragma unroll
    for (int t = 0; t < 8; t++) v[t] = tile[jp + t][d];
    *(ushort8_t*)&Vt[((long)(b * 12 + h) * 64 + d) * 1024 + j0 + jp] = v;
  }
}

// ---------------- NT GEMM (projections / out-proj) ----------------
template <int BM, int BN, bool OUT_F32, bool BIAS>
__global__ __launch_bounds__(256) void gemm_nt(const unsigned short* __restrict__ A, int lda,
                                               const unsigned short* __restrict__ B, int ldb,
                                               void* __restrict__ Cv, int ldc,
                                               const float* __restrict__ bias,
                                               int M, int N, int K) {
  constexpr int BK = 32;
  constexpr int LDT = BK + 8;
  __shared__ unsigned short As[BM][LDT];
  __shared__ unsigned short Bs[BN][LDT];
  const int m0 = blockIdx.y * BM;
  const int n0 = blockIdx.x * BN;
  const int tid = threadIdx.x;
  const int lane = tid & 63;
  const int w = tid >> 6;
  constexpr int WM = BM / 2, WN = BN / 2;
  constexpr int FM = WM / 16, FN = WN / 16;
  const int wr = w >> 1, wc = w & 1;

  f32x4 acc[FM][FN];
  #pragma unroll
  for (int a = 0; a < FM; a++)
    #pragma unroll
    for (int b2 = 0; b2 < FN; b2++) acc[a][b2] = (f32x4){0.f, 0.f, 0.f, 0.f};

  const int rl = lane & 15;
  const int kq = (lane >> 4) * 8;

  for (int k0 = 0; k0 < K; k0 += BK) {
    __syncthreads();
    for (int c = tid; c < BM * (BK / 8); c += 256) {
      int row = c >> 2, kp = (c & 3) * 8;
      *(ushort8_t*)&As[row][kp] = *(const ushort8_t*)&A[(long)(m0 + row) * lda + k0 + kp];
    }
    for (int c = tid; c < BN * (BK / 8); c += 256) {
      int row = c >> 2, kp = (c & 3) * 8;
      *(ushort8_t*)&Bs[row][kp] = *(const ushort8_t*)&B[(long)(n0 + row) * ldb + k0 + kp];
    }
    __syncthreads();
    short8_t af[FM], bfr[FN];
    #pragma unroll
    for (int fm = 0; fm < FM; fm++) af[fm] = *(const short8_t*)&As[wr * WM + fm * 16 + rl][kq];
    #pragma unroll
    for (int fn = 0; fn < FN; fn++) bfr[fn] = *(const short8_t*)&Bs[wc * WN + fn * 16 + rl][kq];
    #pragma unroll
    for (int fm = 0; fm < FM; fm++)
      #pragma unroll
      for (int fn = 0; fn < FN; fn++)
        acc[fm][fn] = __builtin_amdgcn_mfma_f32_16x16x32_bf16(af[fm], bfr[fn], acc[fm][fn], 0, 0, 0);
  }

  const int rq4 = (lane >> 4) * 4;
  #pragma unroll
  for (int fm = 0; fm < FM; fm++)
    #pragma unroll
    for (int fn = 0; fn < FN; fn++)
      #pragma unroll
      for (int j = 0; j < 4; j++) {
        int row = m0 + wr * WM + fm * 16 + rq4 + j;
        int col = n0 + wc * WN + fn * 16 + rl;
        float v = acc[fm][fn][j];
        if (BIAS) v += bias[col];
        if (OUT_F32)
          ((float*)Cv)[(long)row * ldc + col] = v;
        else
          ((unsigned short*)Cv)[(long)row * ldc + col] = f32_to_bf16_rne(v);
      }
}

// ---------------- fused talking-heads attention ----------------
// Block: 256 thr (4 waves), owns (b, 32 i-rows), loops j-tiles of 32 over N=1024.
// Pass 1: QK^T (12 heads) + mix_pre -> l_g row-sums (no max needed: |logit| <~ 6).
// Pass 2: recompute QK + mix -> P = exp/l -> mix_post -> P'' bf16 -> PV accumulate.
// Waves: (mi = i-half, jw = j-strip of 16) for QK; g2-triples for PV.
__global__ __launch_bounds__(256, 1) void fused_attn_kernel(
    const unsigned short* __restrict__ Qb,   // [8*1024][768] bf16
    const unsigned short* __restrict__ KVb,  // [8*1024][1536] bf16 (K = cols 0..767)
    const unsigned short* __restrict__ Vt,   // [8][12][64][1024] bf16
    const float* __restrict__ mix_pre, const float* __restrict__ mix_post,
    unsigned short* __restrict__ AO) {       // [8*1024][768] bf16
  __shared__ unsigned short Q_s[32 * 768];   // 48 KB, row-major, slot-XOR swizzled
  __shared__ unsigned short KV_s[24576];     // 48 KB union: K-tile [32][768] / V-tile [12][64][32] / l-red
  __shared__ unsigned short P_s[12 * 32 * 32]; // 24 KB P'' tiles
  __shared__ float mpre_s[144], mpost_s[144];

  const int b = blockIdx.y;
  const int i0 = blockIdx.x * 32;
  const int tid = threadIdx.x;
  const int lane = tid & 63;
  const int w = tid >> 6;
  const int mi = w >> 1, jw = w & 1;
  const int r15 = lane & 15, q = lane >> 4;

  if (tid < 144) { mpre_s[tid] = mix_pre[tid] * SCALE; mpost_s[tid] = mix_post[tid]; }

  // stage Q once: row = tid>>3, 12 slots of 8 bf16 each; slot' = slot ^ (row&7)
  {
    const int row = tid >> 3;
    const long gbase = (long)(b * 1024 + i0 + row) * 768;
    #pragma unroll
    for (int t = 0; t < 12; ++t) {
      int c8 = (tid & 7) + 8 * t;
      *(ushort8_t*)&Q_s[row * 768 + ((c8 ^ (row & 7)) << 3)] =
          *(const ushort8_t*)&Qb[gbase + c8 * 8];
    }
  }

  const int qrow = mi * 16 + r15;
  const int krow = jw * 16 + r15;
  const int qxor = qrow & 7, kxor = krow & 7;
  const int pvslot = q ^ (r15 & 3);   // PV-side slot swizzle

  auto stage_K = [&](int jt) {
    const int row = tid >> 3;
    const long gbase = (long)(b * 1024 + jt * 32 + row) * 1536;
    #pragma unroll
    for (int t = 0; t < 12; ++t) {
      int c8 = (tid & 7) + 8 * t;
      *(ushort8_t*)&KV_s[row * 768 + ((c8 ^ (row & 7)) << 3)] =
          *(const ushort8_t*)&KVb[gbase + c8 * 8];
    }
  };

  // QK^T for all 12 heads on this wave's [16 i][16 j] patch + mix_pre fold.
  // C-frag: row_local = (lane>>4)*4+e, col_local = lane&15.
  auto qk_mix = [&](float (&macc)[12][4]) {
    #pragma unroll
    for (int g = 0; g < 12; ++g)
      #pragma unroll
      for (int e = 0; e < 4; ++e) macc[g][e] = 0.f;
    #pragma unroll
    for (int h = 0; h < 12; ++h) {
      f32x4 d = {0.f, 0.f, 0.f, 0.f};
      #pragma unroll
      for (int s = 0; s < 2; ++s) {
        int c8 = h * 8 + s * 4 + q;
        short8_t a  = *(const short8_t*)&Q_s[qrow * 768 + ((c8 ^ qxor) << 3)];
        short8_t bb = *(const short8_t*)&KV_s[krow * 768 + ((c8 ^ kxor) << 3)];
        d = __builtin_amdgcn_mfma_f32_16x16x32_bf16(a, bb, d, 0, 0, 0);
      }
      #pragma unroll
      for (int g = 0; g < 12; ++g) {
        float wgt = mpre_s[h * 12 + g];
        #pragma unroll
        for (int e = 0; e < 4; ++e) macc[g][e] += wgt * d[e];
      }
    }
  };

  // ---------------- pass 1: l_g ----------------
  float lsum[12][4];
  #pragma unroll
  for (int g = 0; g < 12; ++g)
    #pragma unroll
    for (int e = 0; e < 4; ++e) lsum[g][e] = 0.f;

  for (int jt = 0; jt < 32; ++jt) {
    __syncthreads();
    stage_K(jt);
    __syncthreads();
    float macc[12][4];
    qk_mix(macc);
    #pragma unroll
    for (int g = 0; g < 12; ++g)
      #pragma unroll
      for (int e = 0; e < 4; ++e) lsum[g][e] += __expf(macc[g][e]);
  }

  // reduce over the 16 j-columns (lanes 0..15 of each quarter)
  #pragma unroll
  for (int off = 1; off < 16; off <<= 1)
    #pragma unroll
    for (int g = 0; g < 12; ++g)
      #pragma unroll
      for (int e = 0; e < 4; ++e) lsum[g][e] += __shfl_xor(lsum[g][e], off);

  __syncthreads();  // K region free -> reuse as reduction scratch
  {
    float* red = (float*)KV_s;
    const int base = (w * 64 + lane) * 48;
    #pragma unroll
    for (int g = 0; g < 12; ++g)
      #pragma unroll
      for (int e = 0; e < 4; ++e) red[base + g * 4 + e] = lsum[g][e];
  }
  __syncthreads();
  float invl[12][4];
  {
    const float* red = (const float*)KV_s;
    const int pbase = ((w ^ 1) * 64 + lane) * 48;  // partner j-strip wave, same mi
    #pragma unroll
    for (int g = 0; g < 12; ++g)
      #pragma unroll
      for (int e = 0; e < 4; ++e)
        invl[g][e] = 1.f / (lsum[g][e] + red[pbase + g * 4 + e]);
  }

  // ---------------- pass 2: P'' + PV ----------------
  f32x4 oacc[3][2][4];
  #pragma unroll
  for (int a = 0; a < 3; ++a)
    #pragma unroll
    for (int m = 0; m < 2; ++m)
      #pragma unroll
      for (int n = 0; n < 4; ++n) oacc[a][m][n] = (f32x4){0.f, 0.f, 0.f, 0.f};

  for (int jt = 0; jt < 32; ++jt) {
    __syncthreads();   // protects KV region (l-red reads / prev V reads)
    stage_K(jt);
    __syncthreads();
    float macc[12][4];
    qk_mix(macc);

    // P''[g2] = sum_g mpost[g,g2] * exp(M_g)/l_g  -> bf16 into P_s (swizzled)
    #pragma unroll
    for (int e = 0; e < 4; ++e) {
      float pe[12];
      #pragma unroll
      for (int g = 0; g < 12; ++g) pe[g] = __expf(macc[g][e]) * invl[g][e];
      const int prow = mi * 16 + q * 4 + e;
      const int slot = (jw * 2 + (r15 >> 3)) ^ (prow & 3);
      const int poff = prow * 32 + slot * 8 + (r15 & 7);
      #pragma unroll
      for (int g2 = 0; g2 < 12; ++g2) {
        float o = 0.f;
        #pragma unroll
        for (int g = 0; g < 12; ++g) o += mpost_s[g * 12 + g2] * pe[g];
        P_s[g2 * 1024 + poff] = f32_to_bf16_rne(o);
      }
    }
    __syncthreads();   // P ready; K region free

    // stage V-tile [12][64][32] (rows 64B, slot' = slot ^ (d&3))
    #pragma unroll
    for (int t = 0; t < 12; ++t) {
      int idx = tid + t * 256;
      int gd = idx >> 2, jj8 = idx & 3;
      int g = gd >> 6, d = gd & 63;
      *(ushort8_t*)&KV_s[gd * 32 + ((jj8 ^ (d & 3)) << 3)] =
          *(const ushort8_t*)&Vt[(((long)(b * 12 + g) * 64 + d) << 10) + jt * 32 + jj8 * 8];
    }
    __syncthreads();

    // PV: wave handles g2 = w*3 .. w*3+2; K-dim = 32 j (single MFMA step)
    #pragma unroll
    for (int g2r = 0; g2r < 3; ++g2r) {
      const int g2 = w * 3 + g2r;
      short8_t af0 = *(const short8_t*)&P_s[g2 * 1024 + r15 * 32 + (pvslot << 3)];
      short8_t af1 = *(const short8_t*)&P_s[g2 * 1024 + (16 + r15) * 32 + (pvslot << 3)];
      short8_t bfv[4];
      #pragma unroll
      for (int nf = 0; nf < 4; ++nf)
        bfv[nf] = *(const short8_t*)&KV_s[(g2 * 64 + nf * 16 + r15) * 32 + (pvslot << 3)];
      #pragma unroll
      for (int nf = 0; nf < 4; ++nf) {
        oacc[g2r][0][nf] = __builtin_amdgcn_mfma_f32_16x16x32_bf16(af0, bfv[nf], oacc[g2r][0][nf], 0, 0, 0);
        oacc[g2r][1][nf] = __builtin_amdgcn_mfma_f32_16x16x32_bf16(af1, bfv[nf], oacc[g2r][1][nf], 0, 0, 0);
      }
    }
  }

  // write AO (bf16): row = i0 + mf*16 + q*4+e, col = g2*64 + nf*16 + r15
  #pragma unroll
  for (int g2r = 0; g2r < 3; ++g2r) {
    const int g2 = w * 3 + g2r;
    #pragma unroll
    for (int mf = 0; mf < 2; ++mf)
      #pragma unroll
      for (int nf = 0; nf < 4; ++nf)
        #pragma unroll
        for (int e = 0; e < 4; ++e) {
          int row = i0 + mf * 16 + q * 4 + e;
          int col = g2 * 64 + nf * 16 + r15;
          AO[(long)(b * 1024 + row) * 768 + col] = f32_to_bf16_rne(oacc[g2r][mf][nf][e]);
        }
  }
}

// ---------------- host launch ----------------
extern "C" void kernel_launch(void* const* d_in, const int* in_sizes, int n_in,
                              void* d_out, int out_size, void* d_ws, size_t ws_size,
                              hipStream_t stream) {
  const float* x        = (const float*)d_in[0];
  const float* W_q      = (const float*)d_in[1];
  const float* W_kv     = (const float*)d_in[2];
  const float* mix_pre  = (const float*)d_in[3];
  const float* mix_post = (const float*)d_in[4];
  const float* W_out    = (const float*)d_in[5];
  const float* b_out    = (const float*)d_in[6];
  float* out = (float*)d_out;

  char* p = (char*)d_ws;
  auto alloc = [&](size_t bytes) { char* r = p; p += (bytes + 255) & ~(size_t)255; return r; };
  unsigned short* xb    = (unsigned short*)alloc(8192ull * 768 * 2);
  unsigned short* WqT   = (unsigned short*)alloc(768ull * 768 * 2);
  unsigned short* WkvT  = (unsigned short*)alloc(1536ull * 768 * 2);
  unsigned short* WoutT = (unsigned short*)alloc(768ull * 768 * 2);
  unsigned short* Qb    = (unsigned short*)alloc(8192ull * 768 * 2);
  unsigned short* KVb   = (unsigned short*)alloc(8192ull * 1536 * 2);
  unsigned short* Vt    = (unsigned short*)alloc(8ull * 12 * 64 * 1024 * 2);
  unsigned short* AO    = (unsigned short*)alloc(8192ull * 768 * 2);

  // 1) casts / transposes
  cast_x_kernel<<<6144, 256, 0, stream>>>((const float4*)x, (ushort4*)xb, 8192 * 768 / 4);
  transpose_cast_kernel<<<dim3(24, 24), 256, 0, stream>>>(W_q, WqT, 768, 768);
  transpose_cast_kernel<<<dim3(48, 24), 256, 0, stream>>>(W_kv, WkvT, 768, 1536);
  transpose_cast_kernel<<<dim3(24, 24), 256, 0, stream>>>(W_out, WoutT, 768, 768);

  // 2) projections
  gemm_nt<128, 128, false, false><<<dim3(6, 64), 256, 0, stream>>>(
      xb, 768, WqT, 768, Qb, 768, nullptr, 8192, 768, 768);
  gemm_nt<128, 128, false, false><<<dim3(12, 64), 256, 0, stream>>>(
      xb, 768, WkvT, 768, KVb, 1536, nullptr, 8192, 1536, 768);

  // 3) V transpose
  transpose_v_kernel<<<dim3(16, 12, 8), 256, 0, stream>>>(KVb, Vt);

  // 4) fused talking-heads attention (no dots / attnP materialization)
  fused_attn_kernel<<<dim3(32, 8), 256, 0, stream>>>(Qb, KVb, Vt, mix_pre, mix_post, AO);

  // 5) out = AO @ WoutT^T + b_out (fp32 out)
  gemm_nt<128, 128, true, true><<<dim3(6, 64), 256, 0, stream>>>(
      AO, 768, WoutT, 768, out, 768, b_out, 8192, 768, 768);
}

// Round 4
// 882.235 us; speedup vs baseline: 1.4648x; 1.4648x over previous
//
#include <hip/hip_runtime.h>
#include <hip/hip_bf16.h>

typedef __attribute__((ext_vector_type(8))) short short8_t;
typedef __attribute__((ext_vector_type(8))) unsigned short ushort8_t;
typedef __attribute__((ext_vector_type(4))) float f32x4;

#define SCALE 0.125f   // 64^-0.5

__device__ __forceinline__ unsigned short f32_to_bf16_rne(float f) {
  unsigned int u = __float_as_uint(f);
  unsigned int r = 0x7FFFu + ((u >> 16) & 1u);
  return (unsigned short)((u + r) >> 16);
}

// bank-spread swizzle for 64B rows (32 j * bf16): slot' = slot ^ swz(row)
__device__ __forceinline__ int swz(int i) { return (i + (i >> 2)) & 3; }

// ---------------- cast x (fp32 -> bf16) ----------------
__global__ __launch_bounds__(256) void cast_x_kernel(const float4* __restrict__ in,
                                                     ushort4* __restrict__ out, int n4) {
  int i = blockIdx.x * 256 + threadIdx.x;
  if (i < n4) {
    float4 v = in[i];
    ushort4 o;
    o.x = f32_to_bf16_rne(v.x); o.y = f32_to_bf16_rne(v.y);
    o.z = f32_to_bf16_rne(v.z); o.w = f32_to_bf16_rne(v.w);
    out[i] = o;
  }
}

// ---------------- transpose + cast weights: in R x C fp32 -> out C x R bf16 ----------------
__global__ __launch_bounds__(256) void transpose_cast_kernel(const float* __restrict__ in,
                                                             unsigned short* __restrict__ out,
                                                             int R, int C) {
  __shared__ float tile[32][33];
  int c0 = blockIdx.x * 32, r0 = blockIdx.y * 32;
  int tx = threadIdx.x & 31, ty = threadIdx.x >> 5;  // 32 x 8
  #pragma unroll
  for (int i = ty; i < 32; i += 8)
    tile[i][tx] = in[(long)(r0 + i) * C + c0 + tx];
  __syncthreads();
  #pragma unroll
  for (int i = ty; i < 32; i += 8)
    out[(long)(c0 + i) * R + r0 + tx] = f32_to_bf16_rne(tile[tx][i]);
}

// ---------------- transpose V out of KV buffer: Vt[b][h][d][j] = KV[b*1024+j][768+h*64+d] ----------------
__global__ __launch_bounds__(256) void transpose_v_kernel(const unsigned short* __restrict__ KV,
                                                          unsigned short* __restrict__ Vt) {
  __shared__ unsigned short tile[64][72];
  const int j0 = blockIdx.x * 64, h = blockIdx.y, b = blockIdx.z;
  const int tid = threadIdx.x;
  for (int c = tid; c < 512; c += 256) {
    int j = c >> 3, dp = (c & 7) * 8;
    *(ushort8_t*)&tile[j][dp] =
        *(const ushort8_t*)&KV[(long)(b * 1024 + j0 + j) * 1536 + 768 + h * 64 + dp];
  }
  __syncthreads();
  for (int c = tid; c < 512; c += 256) {
    int d = c >> 3, jp = (c & 7) * 8;
    ushort8_t v;
    #pragma unroll
    for (int t = 0; t < 8; t++) v[t] = tile[jp + t][d];
    *(ushort8_t*)&Vt[((long)(b * 12 + h) * 64 + d) * 1024 + j0 + jp] = v;
  }
}

// ---------------- NT GEMM (projections / out-proj) ----------------
template <int BM, int BN, bool OUT_F32, bool BIAS>
__global__ __launch_bounds__(256) void gemm_nt(const unsigned short* __restrict__ A, int lda,
                                               const unsigned short* __restrict__ B, int ldb,
                                               void* __restrict__ Cv, int ldc,
                                               const float* __restrict__ bias,
                                               int M, int N, int K) {
  constexpr int BK = 32;
  constexpr int LDT = BK + 8;
  __shared__ unsigned short As[BM][LDT];
  __shared__ unsigned short Bs[BN][LDT];
  const int m0 = blockIdx.y * BM;
  const int n0 = blockIdx.x * BN;
  const int tid = threadIdx.x;
  const int lane = tid & 63;
  const int w = tid >> 6;
  constexpr int WM = BM / 2, WN = BN / 2;
  constexpr int FM = WM / 16, FN = WN / 16;
  const int wr = w >> 1, wc = w & 1;

  f32x4 acc[FM][FN];
  #pragma unroll
  for (int a = 0; a < FM; a++)
    #pragma unroll
    for (int b2 = 0; b2 < FN; b2++) acc[a][b2] = (f32x4){0.f, 0.f, 0.f, 0.f};

  const int rl = lane & 15;
  const int kq = (lane >> 4) * 8;

  for (int k0 = 0; k0 < K; k0 += BK) {
    __syncthreads();
    for (int c = tid; c < BM * (BK / 8); c += 256) {
      int row = c >> 2, kp = (c & 3) * 8;
      *(ushort8_t*)&As[row][kp] = *(const ushort8_t*)&A[(long)(m0 + row) * lda + k0 + kp];
    }
    for (int c = tid; c < BN * (BK / 8); c += 256) {
      int row = c >> 2, kp = (c & 3) * 8;
      *(ushort8_t*)&Bs[row][kp] = *(const ushort8_t*)&B[(long)(n0 + row) * ldb + k0 + kp];
    }
    __syncthreads();
    short8_t af[FM], bfr[FN];
    #pragma unroll
    for (int fm = 0; fm < FM; fm++) af[fm] = *(const short8_t*)&As[wr * WM + fm * 16 + rl][kq];
    #pragma unroll
    for (int fn = 0; fn < FN; fn++) bfr[fn] = *(const short8_t*)&Bs[wc * WN + fn * 16 + rl][kq];
    #pragma unroll
    for (int fm = 0; fm < FM; fm++)
      #pragma unroll
      for (int fn = 0; fn < FN; fn++)
        acc[fm][fn] = __builtin_amdgcn_mfma_f32_16x16x32_bf16(af[fm], bfr[fn], acc[fm][fn], 0, 0, 0);
  }

  const int rq4 = (lane >> 4) * 4;
  #pragma unroll
  for (int fm = 0; fm < FM; fm++)
    #pragma unroll
    for (int fn = 0; fn < FN; fn++)
      #pragma unroll
      for (int j = 0; j < 4; j++) {
        int row = m0 + wr * WM + fm * 16 + rq4 + j;
        int col = n0 + wc * WN + fn * 16 + rl;
        float v = acc[fm][fn][j];
        if (BIAS) v += bias[col];
        if (OUT_F32)
          ((float*)Cv)[(long)row * ldc + col] = v;
        else
          ((unsigned short*)Cv)[(long)row * ldc + col] = f32_to_bf16_rne(v);
      }
}

// ---------------- X: QK^T (per-head) + mix_pre + exp -> E tiles + partial row sums ----------------
// Block = (jt, it, z): 64 i-rows x 32 j-cols, all 12 heads.
// E layout: [z][jt(32)][it(16)] contiguous 48KB chunks, each = swizzled LDS image
//           [g(12)][i(64)][j(32)] bf16, slot16' = (j>>3) ^ swz(i).
// Lpart layout: [z][jt][g][i_global(1024)] fp32.
__global__ __launch_bounds__(256, 3) void qk_mix_exp_kernel(
    const unsigned short* __restrict__ Qb, const unsigned short* __restrict__ KVb,
    const float* __restrict__ mix_pre,
    unsigned short* __restrict__ Eo, float* __restrict__ Lpart, int b_base) {
  __shared__ unsigned short buf[24576];   // 48KB: per-h staging (12KB) then E repack (48KB)
  __shared__ float mpre_s[144];
  const int jt = blockIdx.x, it = blockIdx.y, z = blockIdx.z;
  const int b = b_base + z;
  const int tid = threadIdx.x, lane = tid & 63, w = tid >> 6;
  const int r15 = lane & 15, q = lane >> 4;
  if (tid < 144) mpre_s[tid] = mix_pre[tid] * SCALE;

  const int i0 = it * 64, j0 = jt * 32;
  // staging: Q-tile [64 i][64 d] (8KB), K-tile [32 j][64 d] (4KB) per head
  const int qrow = tid >> 2, qs = (tid & 3) * 2;   // 4 thr/row, 2 slots (16B) each
  const int krow = tid >> 3, ks = tid & 7;         // 8 thr/row, 1 slot each
  const long qg = (long)(b * 1024 + i0 + qrow) * 768;
  const long kg = (long)(b * 1024 + j0 + krow) * 1536;

  ushort8_t pq0 = *(const ushort8_t*)&Qb[qg + qs * 8];
  ushort8_t pq1 = *(const ushort8_t*)&Qb[qg + qs * 8 + 8];
  ushort8_t pk0 = *(const ushort8_t*)&KVb[kg + ks * 8];

  float macc[12][2][4];
  #pragma unroll
  for (int g = 0; g < 12; ++g)
    #pragma unroll
    for (int nf = 0; nf < 2; ++nf)
      #pragma unroll
      for (int e = 0; e < 4; ++e) macc[g][nf][e] = 0.f;

  for (int h = 0; h < 12; ++h) {
    __syncthreads();
    *(ushort8_t*)&buf[qrow * 64 + ((qs ^ (qrow & 7)) << 3)] = pq0;
    *(ushort8_t*)&buf[qrow * 64 + (((qs + 1) ^ (qrow & 7)) << 3)] = pq1;
    *(ushort8_t*)&buf[4096 + krow * 64 + ((ks ^ (krow & 7)) << 3)] = pk0;
    if (h < 11) {  // prefetch next head while computing this one
      pq0 = *(const ushort8_t*)&Qb[qg + (h + 1) * 64 + qs * 8];
      pq1 = *(const ushort8_t*)&Qb[qg + (h + 1) * 64 + qs * 8 + 8];
      pk0 = *(const ushort8_t*)&KVb[kg + (h + 1) * 64 + ks * 8];
    }
    __syncthreads();
    const int ar = w * 16 + r15, ax = ar & 7;
    short8_t a0 = *(const short8_t*)&buf[ar * 64 + ((q ^ ax) << 3)];
    short8_t a1 = *(const short8_t*)&buf[ar * 64 + (((4 + q) ^ ax) << 3)];
    f32x4 h0 = {0.f, 0.f, 0.f, 0.f}, h1 = {0.f, 0.f, 0.f, 0.f};
    {
      const int br = r15, bx = br & 7;
      short8_t b0 = *(const short8_t*)&buf[4096 + br * 64 + ((q ^ bx) << 3)];
      short8_t b1 = *(const short8_t*)&buf[4096 + br * 64 + (((4 + q) ^ bx) << 3)];
      h0 = __builtin_amdgcn_mfma_f32_16x16x32_bf16(a0, b0, h0, 0, 0, 0);
      h0 = __builtin_amdgcn_mfma_f32_16x16x32_bf16(a1, b1, h0, 0, 0, 0);
    }
    {
      const int br = 16 + r15, bx = br & 7;
      short8_t b0 = *(const short8_t*)&buf[4096 + br * 64 + ((q ^ bx) << 3)];
      short8_t b1 = *(const short8_t*)&buf[4096 + br * 64 + (((4 + q) ^ bx) << 3)];
      h1 = __builtin_amdgcn_mfma_f32_16x16x32_bf16(a0, b0, h1, 0, 0, 0);
      h1 = __builtin_amdgcn_mfma_f32_16x16x32_bf16(a1, b1, h1, 0, 0, 0);
    }
    #pragma unroll
    for (int g = 0; g < 12; ++g) {
      const float wgt = mpre_s[h * 12 + g];
      #pragma unroll
      for (int e = 0; e < 4; ++e) {
        macc[g][0][e] += wgt * h0[e];
        macc[g][1][e] += wgt * h1[e];
      }
    }
  }

  // exp
  #pragma unroll
  for (int g = 0; g < 12; ++g)
    #pragma unroll
    for (int nf = 0; nf < 2; ++nf)
      #pragma unroll
      for (int e = 0; e < 4; ++e) macc[g][nf][e] = __expf(macc[g][nf][e]);

  // partial row sums over this block's 32 j  (in-lane nf + 16-lane shuffle)
  float ls[12][4];
  #pragma unroll
  for (int g = 0; g < 12; ++g)
    #pragma unroll
    for (int e = 0; e < 4; ++e) ls[g][e] = macc[g][0][e] + macc[g][1][e];
  #pragma unroll
  for (int off = 1; off < 16; off <<= 1)
    #pragma unroll
    for (int g = 0; g < 12; ++g)
      #pragma unroll
      for (int e = 0; e < 4; ++e) ls[g][e] += __shfl_xor(ls[g][e], off);
  #pragma unroll
  for (int g = 0; g < 12; ++g)
    if (r15 == g) {
      #pragma unroll
      for (int e = 0; e < 4; ++e)
        Lpart[((long)(z * 32 + jt) * 12 + g) * 1024 + i0 + w * 16 + q * 4 + e] = ls[g][e];
    }

  // repack E to LDS (swizzled) then stream 48KB contiguous to global
  __syncthreads();
  #pragma unroll
  for (int g = 0; g < 12; ++g)
    #pragma unroll
    for (int nf = 0; nf < 2; ++nf)
      #pragma unroll
      for (int e = 0; e < 4; ++e) {
        const int il = w * 16 + q * 4 + e, j = nf * 16 + r15;
        buf[g * 2048 + il * 32 + (((j >> 3) ^ swz(il)) << 3) + (j & 7)] =
            f32_to_bf16_rne(macc[g][nf][e]);
      }
  __syncthreads();
  unsigned short* Ech = Eo + ((long)((z * 32 + jt) * 16 + it)) * 24576;
  #pragma unroll
  for (int u = 0; u < 12; ++u)
    *(ushort8_t*)&Ech[tid * 96 + u * 8] = *(const ushort8_t*)&buf[tid * 96 + u * 8];
}

// ---------------- Y: invl[z][g][i] = 1 / sum_jt Lpart ----------------
__global__ __launch_bounds__(256) void lsum_kernel(const float* __restrict__ Lpart,
                                                   float* __restrict__ invl, int nb) {
  int id = blockIdx.x * 256 + threadIdx.x;
  if (id >= nb * 12288) return;
  int z = id / 12288, r = id - z * 12288;
  float s = 0.f;
  #pragma unroll 4
  for (int jt = 0; jt < 32; ++jt) s += Lpart[((long)(z * 32 + jt)) * 12288 + r];
  invl[id] = 1.f / s;
}

// ---------------- Z: P'' build (mix_post * invl * E) + PV MFMA ----------------
// Block = (g2-group, it, z): out rows it*64..+63, cols (g2 group)*64 each.
template <int G2G>
__global__ __launch_bounds__(256, 2) void pv_kernel(
    const unsigned short* __restrict__ E, const unsigned short* __restrict__ Vt,
    const float* __restrict__ invl, const float* __restrict__ mix_post,
    unsigned short* __restrict__ AO, int b_base) {
  constexpr int NG = (G2G == 4) ? 2 : 1;   // g2 per wave
  constexpr int ND = (G2G == 4) ? 4 : 2;   // d-frags per (wave, g2)
  __shared__ unsigned short Ebuf[24576];      // 48KB, verbatim E chunk
  __shared__ unsigned short Pbuf[G2G * 2048]; // [G2G][64 i][32 j] swizzled
  __shared__ unsigned short Vbuf[G2G * 2048]; // [G2G][64 d][32 j] swizzled
  const int g20 = blockIdx.x * G2G;
  const int it = blockIdx.y, z = blockIdx.z, b = b_base + z;
  const int tid = threadIdx.x, lane = tid & 63, w = tid >> 6;
  const int r15 = lane & 15, q = lane >> 4;
  const int wi = w >> 1, wsec = w & 1;
  const int i_t = tid & 63, jg = tid >> 6;

  // per-thread (fixed i) combined weights: mpost[g,g2] * invl[g,i]
  float W2[G2G][12];
  #pragma unroll
  for (int g = 0; g < 12; ++g) {
    float il = invl[(z * 12 + g) * 1024 + it * 64 + i_t];
    #pragma unroll
    for (int r = 0; r < G2G; ++r) W2[r][g] = mix_post[g * 12 + g20 + r] * il;
  }

  f32x4 acc[2][NG][ND];
  #pragma unroll
  for (int mf = 0; mf < 2; ++mf)
    #pragma unroll
    for (int gl = 0; gl < NG; ++gl)
      #pragma unroll
      for (int df = 0; df < ND; ++df) acc[mf][gl][df] = (f32x4){0.f, 0.f, 0.f, 0.f};

  for (int jt = 0; jt < 32; ++jt) {
    __syncthreads();
    // stage E chunk verbatim (global bytes == swizzled LDS image)
    const unsigned short* Ech = E + ((long)((z * 32 + jt) * 16 + it)) * 24576;
    #pragma unroll
    for (int u = 0; u < 12; ++u)
      *(ushort8_t*)&Ebuf[tid * 96 + u * 8] = *(const ushort8_t*)&Ech[tid * 96 + u * 8];
    // stage V tiles
    if constexpr (G2G == 4) {
      const int g2r = tid >> 6, d = tid & 63;
      const long vg = ((long)((b * 12 + g20 + g2r) * 64 + d)) * 1024 + jt * 32;
      #pragma unroll
      for (int u = 0; u < 4; ++u)
        *(ushort8_t*)&Vbuf[g2r * 2048 + d * 32 + ((u ^ swz(d)) << 3)] =
            *(const ushort8_t*)&Vt[vg + u * 8];
    } else {
      const int d = tid >> 2, u = tid & 3;
      const long vg = ((long)((b * 12 + g20) * 64 + d)) * 1024 + jt * 32;
      *(ushort8_t*)&Vbuf[d * 32 + ((u ^ swz(d)) << 3)] =
          *(const ushort8_t*)&Vt[vg + u * 8];
    }
    __syncthreads();

    // transform: P''[g2][i][j] = sum_g W2 * E
    float p[G2G][8];
    #pragma unroll
    for (int r = 0; r < G2G; ++r)
      #pragma unroll
      for (int jj = 0; jj < 8; ++jj) p[r][jj] = 0.f;
    #pragma unroll
    for (int g = 0; g < 12; ++g) {
      ushort8_t ev = *(const ushort8_t*)&Ebuf[g * 2048 + i_t * 32 + ((jg ^ swz(i_t)) << 3)];
      #pragma unroll
      for (int jj = 0; jj < 8; ++jj) {
        float ef = __uint_as_float((unsigned)ev[jj] << 16);
        #pragma unroll
        for (int r = 0; r < G2G; ++r) p[r][jj] += W2[r][g] * ef;
      }
    }
    #pragma unroll
    for (int r = 0; r < G2G; ++r) {
      ushort8_t pv;
      #pragma unroll
      for (int jj = 0; jj < 8; ++jj) pv[jj] = f32_to_bf16_rne(p[r][jj]);
      *(ushort8_t*)&Pbuf[r * 2048 + i_t * 32 + ((jg ^ swz(i_t)) << 3)] = pv;
    }
    __syncthreads();

    // PV MFMA
    #pragma unroll
    for (int gl = 0; gl < NG; ++gl) {
      const int g2sel = (G2G == 4) ? (wsec * 2 + gl) : 0;
      short8_t af[2], bfv[ND];
      #pragma unroll
      for (int mf = 0; mf < 2; ++mf) {
        const int ar = wi * 32 + mf * 16 + r15;
        af[mf] = *(const short8_t*)&Pbuf[g2sel * 2048 + ar * 32 + ((q ^ swz(ar)) << 3)];
      }
      #pragma unroll
      for (int df = 0; df < ND; ++df) {
        const int dr = ((G2G == 4) ? 0 : wsec * 32) + df * 16 + r15;
        bfv[df] = *(const short8_t*)&Vbuf[g2sel * 2048 + dr * 32 + ((q ^ swz(dr)) << 3)];
      }
      #pragma unroll
      for (int mf = 0; mf < 2; ++mf)
        #pragma unroll
        for (int df = 0; df < ND; ++df)
          acc[mf][gl][df] =
              __builtin_amdgcn_mfma_f32_16x16x32_bf16(af[mf], bfv[df], acc[mf][gl][df], 0, 0, 0);
    }
  }

  // epilogue -> AO bf16
  #pragma unroll
  for (int gl = 0; gl < NG; ++gl) {
    const int g2sel = (G2G == 4) ? (wsec * 2 + gl) : 0;
    #pragma unroll
    for (int mf = 0; mf < 2; ++mf)
      #pragma unroll
      for (int df = 0; df < ND; ++df)
        #pragma unroll
        for (int e = 0; e < 4; ++e) {
          int row = it * 64 + wi * 32 + mf * 16 + q * 4 + e;
          int col = (g20 + g2sel) * 64 + ((G2G == 4) ? 0 : wsec * 32) + df * 16 + r15;
          AO[(long)(b * 1024 + row) * 768 + col] = f32_to_bf16_rne(acc[mf][gl][df][e]);
        }
  }
}

// ---------------- host launch ----------------
extern "C" void kernel_launch(void* const* d_in, const int* in_sizes, int n_in,
                              void* d_out, int out_size, void* d_ws, size_t ws_size,
                              hipStream_t stream) {
  const float* x        = (const float*)d_in[0];
  const float* W_q      = (const float*)d_in[1];
  const float* W_kv     = (const float*)d_in[2];
  const float* mix_pre  = (const float*)d_in[3];
  const float* mix_post = (const float*)d_in[4];
  const float* W_out    = (const float*)d_in[5];
  const float* b_out    = (const float*)d_in[6];
  float* out = (float*)d_out;

  char* p = (char*)d_ws;
  auto alloc = [&](size_t bytes) { char* r = p; p += (bytes + 255) & ~(size_t)255; return r; };
  unsigned short* xb    = (unsigned short*)alloc(8192ull * 768 * 2);
  unsigned short* WqT   = (unsigned short*)alloc(768ull * 768 * 2);
  unsigned short* WkvT  = (unsigned short*)alloc(1536ull * 768 * 2);
  unsigned short* WoutT = (unsigned short*)alloc(768ull * 768 * 2);
  unsigned short* Qb    = (unsigned short*)alloc(8192ull * 768 * 2);
  unsigned short* KVb   = (unsigned short*)alloc(8192ull * 1536 * 2);
  unsigned short* Vt    = (unsigned short*)alloc(8ull * 12 * 64 * 1024 * 2);
  unsigned short* AO    = (unsigned short*)alloc(8192ull * 768 * 2);

  // big path: E for all 8 batches (201MB) -> 3 large dispatches; else per-b loop.
  const bool big = ws_size >= 296000000ull;
  const int nb = big ? 8 : 1;
  unsigned short* E     = (unsigned short*)alloc((size_t)nb * 32 * 16 * 12 * 64 * 32 * 2);
  float*          Lpart = (float*)alloc((size_t)nb * 32 * 12 * 1024 * 4);
  float*          invl  = (float*)alloc((size_t)nb * 12 * 1024 * 4);

  // 1) casts / transposes
  cast_x_kernel<<<6144, 256, 0, stream>>>((const float4*)x, (ushort4*)xb, 8192 * 768 / 4);
  transpose_cast_kernel<<<dim3(24, 24), 256, 0, stream>>>(W_q, WqT, 768, 768);
  transpose_cast_kernel<<<dim3(48, 24), 256, 0, stream>>>(W_kv, WkvT, 768, 1536);
  transpose_cast_kernel<<<dim3(24, 24), 256, 0, stream>>>(W_out, WoutT, 768, 768);

  // 2) projections
  gemm_nt<128, 128, false, false><<<dim3(6, 64), 256, 0, stream>>>(
      xb, 768, WqT, 768, Qb, 768, nullptr, 8192, 768, 768);
  gemm_nt<128, 128, false, false><<<dim3(12, 64), 256, 0, stream>>>(
      xb, 768, WkvT, 768, KVb, 1536, nullptr, 8192, 1536, 768);

  // 3) V transpose
  transpose_v_kernel<<<dim3(16, 12, 8), 256, 0, stream>>>(KVb, Vt);

  // 4) attention middle: X (QK+mix+exp -> E, Lpart), Y (invl), Z (P''+PV)
  if (big) {
    qk_mix_exp_kernel<<<dim3(32, 16, 8), 256, 0, stream>>>(Qb, KVb, mix_pre, E, Lpart, 0);
    lsum_kernel<<<(8 * 12288 + 255) / 256, 256, 0, stream>>>(Lpart, invl, 8);
    pv_kernel<4><<<dim3(3, 16, 8), 256, 0, stream>>>(E, Vt, invl, mix_post, AO, 0);
  } else {
    for (int b = 0; b < 8; ++b) {
      qk_mix_exp_kernel<<<dim3(32, 16, 1), 256, 0, stream>>>(Qb, KVb, mix_pre, E, Lpart, b);
      lsum_kernel<<<48, 256, 0, stream>>>(Lpart, invl, 1);
      pv_kernel<1><<<dim3(12, 16, 1), 256, 0, stream>>>(E, Vt, invl, mix_post, AO, b);
    }
  }

  // 5) out = AO @ WoutT^T + b_out (fp32 out)
  gemm_nt<128, 128, true, true><<<dim3(6, 64), 256, 0, stream>>>(
      AO, 768, WoutT, 768, out, 768, b_out, 8192, 768, 768);
}

// Round 5
// 447.898 us; speedup vs baseline: 2.8852x; 1.9697x over previous
//
#include <hip/hip_runtime.h>
#include <hip/hip_bf16.h>

typedef __attribute__((ext_vector_type(8))) short short8_t;
typedef __attribute__((ext_vector_type(8))) unsigned short ushort8_t;
typedef __attribute__((ext_vector_type(4))) float f32x4;

#define SCALE 0.125f   // 64^-0.5

__device__ __forceinline__ unsigned short f32_to_bf16_rne(float f) {
  unsigned int u = __float_as_uint(f);
  unsigned int r = 0x7FFFu + ((u >> 16) & 1u);
  return (unsigned short)((u + r) >> 16);
}

// bank-spread swizzle for 64B rows (32 j * bf16): slot' = slot ^ swz(row)
__device__ __forceinline__ int swz(int i) { return (i + (i >> 2)) & 3; }

// ---------------- cast x (fp32 -> bf16) ----------------
__global__ __launch_bounds__(256) void cast_x_kernel(const float4* __restrict__ in,
                                                     ushort4* __restrict__ out, int n4) {
  int i = blockIdx.x * 256 + threadIdx.x;
  if (i < n4) {
    float4 v = in[i];
    ushort4 o;
    o.x = f32_to_bf16_rne(v.x); o.y = f32_to_bf16_rne(v.y);
    o.z = f32_to_bf16_rne(v.z); o.w = f32_to_bf16_rne(v.w);
    out[i] = o;
  }
}

// ---------------- transpose + cast weights: in R x C fp32 -> out C x R bf16 ----------------
__global__ __launch_bounds__(256) void transpose_cast_kernel(const float* __restrict__ in,
                                                             unsigned short* __restrict__ out,
                                                             int R, int C) {
  __shared__ float tile[32][33];
  int c0 = blockIdx.x * 32, r0 = blockIdx.y * 32;
  int tx = threadIdx.x & 31, ty = threadIdx.x >> 5;  // 32 x 8
  #pragma unroll
  for (int i = ty; i < 32; i += 8)
    tile[i][tx] = in[(long)(r0 + i) * C + c0 + tx];
  __syncthreads();
  #pragma unroll
  for (int i = ty; i < 32; i += 8)
    out[(long)(c0 + i) * R + r0 + tx] = f32_to_bf16_rne(tile[tx][i]);
}

// ---------------- transpose V: Vt[b][h][d][j] = KV[b*1024+j][768+h*64+d] ----------------
// j-slots (16B) within each 32-j tile are XOR-swizzled by d so pv2 can stage
// linearly and still read bank-conflict-free (pre-swizzled-source pattern).
__global__ __launch_bounds__(256) void transpose_v_kernel(const unsigned short* __restrict__ KV,
                                                          unsigned short* __restrict__ Vt) {
  __shared__ unsigned short tile[64][72];
  const int j0 = blockIdx.x * 64, h = blockIdx.y, b = blockIdx.z;
  const int tid = threadIdx.x;
  for (int c = tid; c < 512; c += 256) {
    int j = c >> 3, dp = (c & 7) * 8;
    *(ushort8_t*)&tile[j][dp] =
        *(const ushort8_t*)&KV[(long)(b * 1024 + j0 + j) * 1536 + 768 + h * 64 + dp];
  }
  __syncthreads();
  for (int c = tid; c < 512; c += 256) {
    int d = c >> 3, jp = (c & 7) * 8;
    ushort8_t v;
    #pragma unroll
    for (int t = 0; t < 8; t++) v[t] = tile[jp + t][d];
    int jg = j0 + jp;
    int jt_ = jg >> 5;            // 32-j tile
    int u = (jg >> 3) & 3;        // 16B slot within tile
    *(ushort8_t*)&Vt[((long)(b * 12 + h) * 64 + d) * 1024 + (jt_ << 5) + ((u ^ swz(d)) << 3)] = v;
  }
}

// ---------------- NT GEMM (projections / out-proj). SUM2: A := A + A2 (bf16) ----------------
template <int BM, int BN, bool OUT_F32, bool BIAS, bool SUM2>
__global__ __launch_bounds__(256) void gemm_nt(const unsigned short* __restrict__ A,
                                               const unsigned short* __restrict__ A2, int lda,
                                               const unsigned short* __restrict__ B, int ldb,
                                               void* __restrict__ Cv, int ldc,
                                               const float* __restrict__ bias,
                                               int M, int N, int K) {
  constexpr int BK = 32;
  constexpr int LDT = BK + 8;
  __shared__ unsigned short As[BM][LDT];
  __shared__ unsigned short Bs[BN][LDT];
  const int m0 = blockIdx.y * BM;
  const int n0 = blockIdx.x * BN;
  const int tid = threadIdx.x;
  const int lane = tid & 63;
  const int w = tid >> 6;
  constexpr int WM = BM / 2, WN = BN / 2;
  constexpr int FM = WM / 16, FN = WN / 16;
  const int wr = w >> 1, wc = w & 1;

  f32x4 acc[FM][FN];
  #pragma unroll
  for (int a = 0; a < FM; a++)
    #pragma unroll
    for (int b2 = 0; b2 < FN; b2++) acc[a][b2] = (f32x4){0.f, 0.f, 0.f, 0.f};

  const int rl = lane & 15;
  const int kq = (lane >> 4) * 8;

  for (int k0 = 0; k0 < K; k0 += BK) {
    __syncthreads();
    for (int c = tid; c < BM * (BK / 8); c += 256) {
      int row = c >> 2, kp = (c & 3) * 8;
      ushort8_t v = *(const ushort8_t*)&A[(long)(m0 + row) * lda + k0 + kp];
      if (SUM2) {
        ushort8_t v2 = *(const ushort8_t*)&A2[(long)(m0 + row) * lda + k0 + kp];
        #pragma unroll
        for (int x = 0; x < 8; ++x)
          v[x] = f32_to_bf16_rne(__uint_as_float((unsigned)v[x] << 16) +
                                 __uint_as_float((unsigned)v2[x] << 16));
      }
      *(ushort8_t*)&As[row][kp] = v;
    }
    for (int c = tid; c < BN * (BK / 8); c += 256) {
      int row = c >> 2, kp = (c & 3) * 8;
      *(ushort8_t*)&Bs[row][kp] = *(const ushort8_t*)&B[(long)(n0 + row) * ldb + k0 + kp];
    }
    __syncthreads();
    short8_t af[FM], bfr[FN];
    #pragma unroll
    for (int fm = 0; fm < FM; fm++) af[fm] = *(const short8_t*)&As[wr * WM + fm * 16 + rl][kq];
    #pragma unroll
    for (int fn = 0; fn < FN; fn++) bfr[fn] = *(const short8_t*)&Bs[wc * WN + fn * 16 + rl][kq];
    #pragma unroll
    for (int fm = 0; fm < FM; fm++)
      #pragma unroll
      for (int fn = 0; fn < FN; fn++)
        acc[fm][fn] = __builtin_amdgcn_mfma_f32_16x16x32_bf16(af[fm], bfr[fn], acc[fm][fn], 0, 0, 0);
  }

  const int rq4 = (lane >> 4) * 4;
  #pragma unroll
  for (int fm = 0; fm < FM; fm++)
    #pragma unroll
    for (int fn = 0; fn < FN; fn++)
      #pragma unroll
      for (int j = 0; j < 4; j++) {
        int row = m0 + wr * WM + fm * 16 + rq4 + j;
        int col = n0 + wc * WN + fn * 16 + rl;
        float v = acc[fm][fn][j];
        if (BIAS) v += bias[col];
        if (OUT_F32)
          ((float*)Cv)[(long)row * ldc + col] = v;
        else
          ((unsigned short*)Cv)[(long)row * ldc + col] = f32_to_bf16_rne(v);
      }
}

// ---------------- X: QK^T (all heads) + mix_pre + exp -> E tiles + partial row sums ----------------
// Block = (jt, it, zc): 64 i x 32 j. K staged ONCE (48KB, swizzle-at-source);
// per-head Q double-buffered (1 sync/head). E chunk = 48KB per (zc,jt,it):
// 4 sub-chunks [g(12)][16 i][32 j] (12KB each, slot16' = jslot ^ swz(i&15)).
__global__ __launch_bounds__(256, 2) void qk_mix_exp_kernel(
    const unsigned short* __restrict__ Qb, const unsigned short* __restrict__ KVb,
    const float* __restrict__ mix_pre,
    unsigned short* __restrict__ Eo, float* __restrict__ Lpart, int b_base) {
  __shared__ unsigned short Kbuf[24576];  // 48KB: K [32 j][96 slots]; reused for E repack
  __shared__ unsigned short Qdb[8192];    // 2 x 8KB: Q-head dbuf [64 i][8 slots]
  __shared__ float mpre_s[144];
  const int jt = blockIdx.x, it = blockIdx.y, z = blockIdx.z;
  const int b = b_base + z;
  const int tid = threadIdx.x, lane = tid & 63, w = tid >> 6;
  const int r15 = lane & 15, q = lane >> 4;
  if (tid < 144) mpre_s[tid] = mix_pre[tid] * SCALE;
  const int i0 = it * 64, j0 = jt * 32;

  // stage K once: 3072 16B-units; content slot s holds global slot s^(j&7)
  ushort8_t kreg[12];
  #pragma unroll
  for (int u = 0; u < 12; ++u) {
    int unit = u * 256 + tid;
    int j = unit / 96, s = unit - j * 96;
    kreg[u] = *(const ushort8_t*)&KVb[(long)(b * 1024 + j0 + j) * 1536 + ((s ^ (j & 7)) << 3)];
  }
  // Q head 0
  ushort8_t qreg[2];
  #pragma unroll
  for (int u = 0; u < 2; ++u) {
    int unit = u * 256 + tid;
    int i = unit >> 3, s = unit & 7;
    qreg[u] = *(const ushort8_t*)&Qb[(long)(b * 1024 + i0 + i) * 768 + ((s ^ (i & 7)) << 3)];
  }
  #pragma unroll
  for (int u = 0; u < 12; ++u) *(ushort8_t*)&Kbuf[(u * 256 + tid) * 8] = kreg[u];
  #pragma unroll
  for (int u = 0; u < 2; ++u) *(ushort8_t*)&Qdb[(u * 256 + tid) * 8] = qreg[u];
  __syncthreads();

  float macc[12][2][4];  // [g][j-frag][e]
  #pragma unroll
  for (int g = 0; g < 12; ++g)
    #pragma unroll
    for (int nf = 0; nf < 2; ++nf)
      #pragma unroll
      for (int e = 0; e < 4; ++e) macc[g][nf][e] = 0.f;

  const int ar = w * 16 + r15, ax = ar & 7;

  for (int h = 0; h < 12; ++h) {
    if (h < 11) {
      #pragma unroll
      for (int u = 0; u < 2; ++u) {
        int unit = u * 256 + tid;
        int i = unit >> 3, s = unit & 7;
        qreg[u] = *(const ushort8_t*)&Qb[(long)(b * 1024 + i0 + i) * 768 + (h + 1) * 64 +
                                         ((s ^ (i & 7)) << 3)];
      }
    }
    const unsigned short* Qcur = &Qdb[(h & 1) * 4096];
    short8_t a0 = *(const short8_t*)&Qcur[ar * 64 + ((q ^ ax) << 3)];
    short8_t a1 = *(const short8_t*)&Qcur[ar * 64 + (((4 + q) ^ ax) << 3)];
    f32x4 h0 = {0.f, 0.f, 0.f, 0.f}, h1 = {0.f, 0.f, 0.f, 0.f};
    {
      const int br = r15, bx = br & 7;
      short8_t b0 = *(const short8_t*)&Kbuf[br * 768 + (((h * 8 + q) ^ bx) << 3)];
      short8_t b1 = *(const short8_t*)&Kbuf[br * 768 + (((h * 8 + 4 + q) ^ bx) << 3)];
      h0 = __builtin_amdgcn_mfma_f32_16x16x32_bf16(a0, b0, h0, 0, 0, 0);
      h0 = __builtin_amdgcn_mfma_f32_16x16x32_bf16(a1, b1, h0, 0, 0, 0);
    }
    {
      const int br = 16 + r15, bx = br & 7;
      short8_t b0 = *(const short8_t*)&Kbuf[br * 768 + (((h * 8 + q) ^ bx) << 3)];
      short8_t b1 = *(const short8_t*)&Kbuf[br * 768 + (((h * 8 + 4 + q) ^ bx) << 3)];
      h1 = __builtin_amdgcn_mfma_f32_16x16x32_bf16(a0, b0, h1, 0, 0, 0);
      h1 = __builtin_amdgcn_mfma_f32_16x16x32_bf16(a1, b1, h1, 0, 0, 0);
    }
    #pragma unroll
    for (int g = 0; g < 12; ++g) {
      const float wgt = mpre_s[h * 12 + g];
      #pragma unroll
      for (int e = 0; e < 4; ++e) {
        macc[g][0][e] += wgt * h0[e];
        macc[g][1][e] += wgt * h1[e];
      }
    }
    if (h < 11) {
      unsigned short* Qnxt = &Qdb[((h + 1) & 1) * 4096];
      #pragma unroll
      for (int u = 0; u < 2; ++u) *(ushort8_t*)&Qnxt[(u * 256 + tid) * 8] = qreg[u];
    }
    __syncthreads();
  }

  // exp (no max needed: mixed-logit |max| small, fp32 headroom ample)
  #pragma unroll
  for (int g = 0; g < 12; ++g)
    #pragma unroll
    for (int nf = 0; nf < 2; ++nf)
      #pragma unroll
      for (int e = 0; e < 4; ++e) macc[g][nf][e] = __expf(macc[g][nf][e]);

  // partial row sums over this block's 32 j
  float ls[12][4];
  #pragma unroll
  for (int g = 0; g < 12; ++g)
    #pragma unroll
    for (int e = 0; e < 4; ++e) ls[g][e] = macc[g][0][e] + macc[g][1][e];
  #pragma unroll
  for (int off = 1; off < 16; off <<= 1)
    #pragma unroll
    for (int g = 0; g < 12; ++g)
      #pragma unroll
      for (int e = 0; e < 4; ++e) ls[g][e] += __shfl_xor(ls[g][e], off);
  #pragma unroll
  for (int g = 0; g < 12; ++g)
    if (r15 == g) {
      #pragma unroll
      for (int e = 0; e < 4; ++e)
        Lpart[((long)(z * 32 + jt) * 12 + g) * 1024 + i0 + w * 16 + q * 4 + e] = ls[g][e];
    }

  // repack E into Kbuf (reuse): [sub=w][g][r=il&15][32 j], slot' = jslot ^ swz(r)
  #pragma unroll
  for (int g = 0; g < 12; ++g)
    #pragma unroll
    for (int nf = 0; nf < 2; ++nf)
      #pragma unroll
      for (int e = 0; e < 4; ++e) {
        const int r = q * 4 + e;
        const int jsl = nf * 2 + (r15 >> 3);
        Kbuf[(w * 12 + g) * 512 + r * 32 + ((jsl ^ swz(r)) << 3) + (r15 & 7)] =
            f32_to_bf16_rne(macc[g][nf][e]);
      }
  __syncthreads();
  const long cb = ((long)((z * 32 + jt) * 16 + it)) * 24576;
  #pragma unroll
  for (int u = 0; u < 12; ++u)
    *(ushort8_t*)&Eo[cb + tid * 96 + u * 8] = *(const ushort8_t*)&Kbuf[tid * 96 + u * 8];
}

// ---------------- Y: invl[zc][g][i] = 1 / sum_jt Lpart ----------------
__global__ __launch_bounds__(256) void lsum_kernel(const float* __restrict__ Lpart,
                                                   float* __restrict__ invl, int nb) {
  int id = blockIdx.x * 256 + threadIdx.x;
  if (id >= nb * 12288) return;
  int z = id / 12288, r = id - z * 12288;
  float s = 0.f;
  #pragma unroll 4
  for (int jt = 0; jt < 32; ++jt) s += Lpart[((long)(z * 32 + jt)) * 12288 + r];
  invl[id] = 1.f / s;
}

// ---------------- Z: P'' build + PV, E read exactly once ----------------
// Block = (it16, jh, zc): 16 i-rows, ALL 12 g2, j in [jh*512, jh*512+512).
// Per jt: stage E sub-chunk (12KB) + V slice (48KB) linearly (reg prefetch,
// swizzle pre-baked); transform -> P''[12][16][32] bf16; 12 MFMA/wave.
__global__ __launch_bounds__(256, 1) void pv2_kernel(
    const unsigned short* __restrict__ E, const unsigned short* __restrict__ Vt,
    const float* __restrict__ invl, const float* __restrict__ mix_post,
    unsigned short* __restrict__ AOp0, unsigned short* __restrict__ AOp1, int b_base) {
  __shared__ unsigned short Ebuf[6144];   // [g][16 i][32 j] swizzled
  __shared__ unsigned short Vbuf[24576];  // [g2*64+d][32 j] swizzled
  __shared__ unsigned short Pbuf[6144];   // [g2][16 i][32 j] swizzled
  const int it = blockIdx.x, jh = blockIdx.y, zc = blockIdx.z;
  const int b = b_base + zc;
  const int tid = threadIdx.x, lane = tid & 63, w = tid >> 6;
  const int r15 = lane & 15, q = lane >> 4;
  const int i_loc = tid & 15, jslot = (tid >> 4) & 3;  // transform mapping; g2-group = w

  // combined weights W2[r][g] = mpost[g, w*3+r] * invl[g, i]
  float W2[3][12];
  #pragma unroll
  for (int g = 0; g < 12; ++g) {
    float il = invl[(zc * 12 + g) * 1024 + it * 16 + i_loc];
    #pragma unroll
    for (int r = 0; r < 3; ++r) W2[r][g] = mix_post[g * 12 + w * 3 + r] * il;
  }

  f32x4 acc[3][4];
  #pragma unroll
  for (int gl = 0; gl < 3; ++gl)
    #pragma unroll
    for (int df = 0; df < 4; ++df) acc[gl][df] = (f32x4){0.f, 0.f, 0.f, 0.f};

  const long vbase = (long)(b * 12) * 64 * 1024;
  ushort8_t ereg[3], vreg[12];
  auto loadE = [&](int jt) {
    const long cbs = ((long)((zc * 32 + jt) * 16 + (it >> 2))) * 24576 + (it & 3) * 6144;
    #pragma unroll
    for (int u = 0; u < 3; ++u)
      ereg[u] = *(const ushort8_t*)&E[cbs + (u * 256 + tid) * 8];
  };
  auto loadV = [&](int jt) {
    #pragma unroll
    for (int u = 0; u < 12; ++u) {
      int unit = u * 256 + tid;  // gd = unit>>2, slot = unit&3
      vreg[u] = *(const ushort8_t*)&Vt[vbase + (long)(unit >> 2) * 1024 + jt * 32 +
                                       ((unit & 3) << 3)];
    }
  };
  const int jt0 = jh * 16;
  loadE(jt0);
  loadV(jt0);

  for (int t = 0; t < 16; ++t) {
    __syncthreads();  // buffers free (prev PV done)
    #pragma unroll
    for (int u = 0; u < 3; ++u) *(ushort8_t*)&Ebuf[(u * 256 + tid) * 8] = ereg[u];
    #pragma unroll
    for (int u = 0; u < 12; ++u) *(ushort8_t*)&Vbuf[(u * 256 + tid) * 8] = vreg[u];
    __syncthreads();  // staged
    if (t < 15) { loadE(jt0 + t + 1); loadV(jt0 + t + 1); }  // prefetch overlaps compute

    // transform: P''[g2][i][j] = sum_g W2[g2][g] * E[g][i][j]
    float p[3][8];
    #pragma unroll
    for (int r = 0; r < 3; ++r)
      #pragma unroll
      for (int jj = 0; jj < 8; ++jj) p[r][jj] = 0.f;
    const int esl = (jslot ^ swz(i_loc)) << 3;
    #pragma unroll
    for (int g = 0; g < 12; ++g) {
      ushort8_t ev = *(const ushort8_t*)&Ebuf[g * 512 + i_loc * 32 + esl];
      #pragma unroll
      for (int jj = 0; jj < 8; ++jj) {
        float ef = __uint_as_float((unsigned)ev[jj] << 16);
        #pragma unroll
        for (int r = 0; r < 3; ++r) p[r][jj] += W2[r][g] * ef;
      }
    }
    #pragma unroll
    for (int r = 0; r < 3; ++r) {
      ushort8_t pv;
      #pragma unroll
      for (int jj = 0; jj < 8; ++jj) pv[jj] = f32_to_bf16_rne(p[r][jj]);
      *(ushort8_t*)&Pbuf[(w * 3 + r) * 512 + i_loc * 32 + esl] = pv;
    }
    __syncthreads();  // P ready

    // PV: wave w owns g2 = w*3 .. w*3+2; k = 32 j per MFMA
    #pragma unroll
    for (int gl = 0; gl < 3; ++gl) {
      const int g2 = w * 3 + gl;
      short8_t af = *(const short8_t*)&Pbuf[g2 * 512 + r15 * 32 + ((q ^ swz(r15)) << 3)];
      #pragma unroll
      for (int df = 0; df < 4; ++df) {
        short8_t bf = *(const short8_t*)&Vbuf[(g2 * 64 + df * 16 + r15) * 32 +
                                              ((q ^ swz(r15)) << 3)];
        acc[gl][df] = __builtin_amdgcn_mfma_f32_16x16x32_bf16(af, bf, acc[gl][df], 0, 0, 0);
      }
    }
  }

  unsigned short* AOp = jh ? AOp1 : AOp0;
  #pragma unroll
  for (int gl = 0; gl < 3; ++gl) {
    const int g2 = w * 3 + gl;
    #pragma unroll
    for (int df = 0; df < 4; ++df)
      #pragma unroll
      for (int e = 0; e < 4; ++e) {
        int row = it * 16 + q * 4 + e;
        int col = g2 * 64 + df * 16 + r15;
        AOp[(long)(b * 1024 + row) * 768 + col] = f32_to_bf16_rne(acc[gl][df][e]);
      }
  }
}

// ---------------- host launch ----------------
extern "C" void kernel_launch(void* const* d_in, const int* in_sizes, int n_in,
                              void* d_out, int out_size, void* d_ws, size_t ws_size,
                              hipStream_t stream) {
  const float* x        = (const float*)d_in[0];
  const float* W_q      = (const float*)d_in[1];
  const float* W_kv     = (const float*)d_in[2];
  const float* mix_pre  = (const float*)d_in[3];
  const float* mix_post = (const float*)d_in[4];
  const float* W_out    = (const float*)d_in[5];
  const float* b_out    = (const float*)d_in[6];
  float* out = (float*)d_out;

  char* p = (char*)d_ws;
  auto alloc = [&](size_t bytes) { char* r = p; p += (bytes + 255) & ~(size_t)255; return r; };
  unsigned short* xb    = (unsigned short*)alloc(8192ull * 768 * 2);
  unsigned short* WqT   = (unsigned short*)alloc(768ull * 768 * 2);
  unsigned short* WkvT  = (unsigned short*)alloc(1536ull * 768 * 2);
  unsigned short* WoutT = (unsigned short*)alloc(768ull * 768 * 2);
  unsigned short* Qb    = (unsigned short*)alloc(8192ull * 768 * 2);
  unsigned short* KVb   = (unsigned short*)alloc(8192ull * 1536 * 2);
  unsigned short* Vt    = (unsigned short*)alloc(8ull * 12 * 64 * 1024 * 2);
  unsigned short* AOp0  = (unsigned short*)alloc(8192ull * 768 * 2);
  unsigned short* AOp1  = (unsigned short*)alloc(8192ull * 768 * 2);

  // chunking: nz batches of E/Lpart in flight per round (ws-gated; nz=2 needs
  // ~146 MB which is proven available).
  const int nz = (ws_size >= 322000000ull) ? 8 : (ws_size >= 211000000ull) ? 4 : 2;
  unsigned short* E     = (unsigned short*)alloc((size_t)nz * 32 * 16 * 24576 * 2);
  float*          Lpart = (float*)alloc((size_t)nz * 32 * 12 * 1024 * 4);
  float*          invl  = (float*)alloc((size_t)nz * 12 * 1024 * 4);

  // 1) casts / transposes
  cast_x_kernel<<<6144, 256, 0, stream>>>((const float4*)x, (ushort4*)xb, 8192 * 768 / 4);
  transpose_cast_kernel<<<dim3(24, 24), 256, 0, stream>>>(W_q, WqT, 768, 768);
  transpose_cast_kernel<<<dim3(48, 24), 256, 0, stream>>>(W_kv, WkvT, 768, 1536);
  transpose_cast_kernel<<<dim3(24, 24), 256, 0, stream>>>(W_out, WoutT, 768, 768);

  // 2) projections
  gemm_nt<128, 128, false, false, false><<<dim3(6, 64), 256, 0, stream>>>(
      xb, nullptr, 768, WqT, 768, Qb, 768, nullptr, 8192, 768, 768);
  gemm_nt<128, 128, false, false, false><<<dim3(12, 64), 256, 0, stream>>>(
      xb, nullptr, 768, WkvT, 768, KVb, 1536, nullptr, 8192, 1536, 768);

  // 3) V transpose (pre-swizzled j-slots)
  transpose_v_kernel<<<dim3(16, 12, 8), 256, 0, stream>>>(KVb, Vt);

  // 4) attention middle, nz batches per round
  for (int b0 = 0; b0 < 8; b0 += nz) {
    qk_mix_exp_kernel<<<dim3(32, 16, nz), 256, 0, stream>>>(Qb, KVb, mix_pre, E, Lpart, b0);
    lsum_kernel<<<nz * 48, 256, 0, stream>>>(Lpart, invl, nz);
    pv2_kernel<<<dim3(64, 2, nz), 256, 0, stream>>>(E, Vt, invl, mix_post, AOp0, AOp1, b0);
  }

  // 5) out = (AOp0 + AOp1) @ WoutT^T + b_out (fp32 out)
  gemm_nt<128, 128, true, true, true><<<dim3(6, 64), 256, 0, stream>>>(
      AOp0, AOp1, 768, WoutT, 768, out, 768, b_out, 8192, 768, 768);
}